// Round 8
// baseline (470.010 us; speedup 1.0000x reference)
//
#include <hip/hip_runtime.h>
#include <hip/hip_cooperative_groups.h>

namespace cg = cooperative_groups;

static constexpr int N = 100000;
static constexpr int E = 3200000;
static constexpr int BUKSHIFT = 8;
static constexpr int BUKSZ = 1 << BUKSHIFT;             // 256 nodes / bucket
static constexpr int BUKMASK = BUKSZ - 1;
static constexpr int NBUK = (N + BUKSZ - 1) / BUKSZ;    // 391
static constexpr int NGRP = 8;                           // reservation groups
static constexpr int SUBCAP = 1536;                      // slots per (bucket,group)
static constexpr int CAP = NGRP * SUBCAP;                // 12288 per bucket
static constexpr int GSTRIDE = 16;                       // pad counters to 64B lines
static constexpr int SC_CHUNK = 8192;
static constexpr int NCHUNK = (E + SC_CHUNK - 1) / SC_CHUNK;   // 391
static constexpr int T = 512;                            // coop block size (8 waves)
static constexpr int NBLK_C = 256;                       // 1 block/CU guaranteed

// ws (4B): binned[NBUK*CAP] | dinv[N] | y1[N] | m[N] | gofs[NBUK*NGRP*GSTRIDE] | partials[NBUK*16]

// ===================== fused cooperative kernel =====================
__global__ __launch_bounds__(T) void k_fused(const int4* __restrict__ rows4,
                                             const int4* __restrict__ cols4,
                                             const float* __restrict__ x,
                                             const float* __restrict__ W1,
                                             const float* __restrict__ W2,
                                             const float* __restrict__ W3,
                                             const float* __restrict__ bias,
                                             int* __restrict__ binned,
                                             int* __restrict__ gofs,
                                             float* __restrict__ dinv,
                                             float* __restrict__ y1,
                                             float* __restrict__ m,
                                             float* __restrict__ partials,
                                             float* __restrict__ out) {
    cg::grid_group grid = cg::this_grid();

    __shared__ int hist[4 * NBUK];
    __shared__ int cnt[512];
    __shared__ int lbase[NBUK];
    __shared__ int gbase[NBUK];
    __shared__ int stag[SC_CHUNK];          // 32KB; re-aliased by later phases
    __shared__ float sP[16], sM[16], sAcc[16];

    const int tid = threadIdx.x;
    const int bid = blockIdx.x;

    // ---------- phase 0: init gofs ----------
    for (int gi = bid * T + tid; gi < NBUK * NGRP; gi += NBLK_C * T) {
        int b = gi / NGRP, g = gi % NGRP;
        gofs[gi * GSTRIDE] = b * CAP + g * SUBCAP;
    }
    __threadfence();
    grid.sync();

    // ---------- phase 1: scatter (grid-stride over edge chunks) ----------
    for (int chunk = bid; chunk < NCHUNK; chunk += NBLK_C) {
        const int g = tid >> 7;                 // 4 hist replica groups
        const int grp = chunk & (NGRP - 1);
        for (int i = tid; i < 4 * NBUK; i += T) hist[i] = 0;
        cnt[tid] = 0;
        __syncthreads();

        const int nI4 = E / 4;
        const int base4 = chunk * (SC_CHUNK / 4);
        int4 r[4], c[4];
        bool vld[4];
        #pragma unroll
        for (int k = 0; k < 4; ++k) {
            int idx = base4 + k * T + tid;
            vld[k] = idx < nI4;
            if (vld[k]) { r[k] = rows4[idx]; c[k] = cols4[idx]; }
        }
        #pragma unroll
        for (int k = 0; k < 4; ++k) if (vld[k]) {
            atomicAdd(&hist[g * NBUK + (c[k].x >> BUKSHIFT)], 1);
            atomicAdd(&hist[g * NBUK + (c[k].y >> BUKSHIFT)], 1);
            atomicAdd(&hist[g * NBUK + (c[k].z >> BUKSHIFT)], 1);
            atomicAdd(&hist[g * NBUK + (c[k].w >> BUKSHIFT)], 1);
        }
        __syncthreads();

        if (tid < NBUK) {
            int h0 = hist[0 * NBUK + tid], h1 = hist[1 * NBUK + tid];
            int h2 = hist[2 * NBUK + tid], h3 = hist[3 * NBUK + tid];
            hist[0 * NBUK + tid] = 0;
            hist[1 * NBUK + tid] = h0;
            hist[2 * NBUK + tid] = h0 + h1;
            hist[3 * NBUK + tid] = h0 + h1 + h2;
            int cc = h0 + h1 + h2 + h3;
            cnt[tid] = cc;
            gbase[tid] = cc ? atomicAdd(&gofs[(tid * NGRP + grp) * GSTRIDE], cc) : 0;
        }
        __syncthreads();
        for (int off = 1; off < 512; off <<= 1) {
            int v = cnt[tid];
            if (tid >= off) v += cnt[tid - off];
            __syncthreads();
            cnt[tid] = v;
            __syncthreads();
        }
        if (tid < NBUK) lbase[tid] = tid ? cnt[tid - 1] : 0;
        __syncthreads();

        #pragma unroll
        for (int k = 0; k < 4; ++k) if (vld[k]) {
            int b, off;
            b = c[k].x >> BUKSHIFT; off = atomicAdd(&hist[g * NBUK + b], 1); stag[lbase[b] + off] = (r[k].x << BUKSHIFT) | (c[k].x & BUKMASK);
            b = c[k].y >> BUKSHIFT; off = atomicAdd(&hist[g * NBUK + b], 1); stag[lbase[b] + off] = (r[k].y << BUKSHIFT) | (c[k].y & BUKMASK);
            b = c[k].z >> BUKSHIFT; off = atomicAdd(&hist[g * NBUK + b], 1); stag[lbase[b] + off] = (r[k].z << BUKSHIFT) | (c[k].z & BUKMASK);
            b = c[k].w >> BUKSHIFT; off = atomicAdd(&hist[g * NBUK + b], 1); stag[lbase[b] + off] = (r[k].w << BUKSHIFT) | (c[k].w & BUKMASK);
        }
        __syncthreads();

        const int eTot = min(SC_CHUNK, E - chunk * SC_CHUNK);
        int s = tid * 16;
        if (s < eTot) {
            int lo = 0, hi = NBUK - 1;
            while (lo < hi) { int mid = (lo + hi + 1) >> 1; if (lbase[mid] <= s) lo = mid; else hi = mid - 1; }
            int b = lo;
            const int e1 = min(s + 16, eTot);
            for (; s < e1; ++s) {
                while (b + 1 < NBUK && lbase[b + 1] <= s) ++b;
                binned[gbase[b] + (s - lbase[b])] = stag[s];
            }
        }
        __syncthreads();   // before LDS reuse next chunk
    }
    __threadfence();
    grid.sync();

    // ---------- phase 2: degree -> dinv, y1 (grid-stride over buckets) ----------
    for (int b = bid; b < NBUK; b += NBLK_C) {
        int* cnt8 = stag;   // [8][BUKSZ]
        for (int i = tid; i < 8 * BUKSZ; i += T) cnt8[i] = 0;
        __syncthreads();
        const int g = tid >> 6;     // 8 replicas
        for (int sg = 0; sg < NGRP; ++sg) {
            const int s0 = b * CAP + sg * SUBCAP;
            const int n = gofs[(b * NGRP + sg) * GSTRIDE] - s0;
            const int n4 = n >> 2;
            const int4* b4 = (const int4*)(binned + s0);
            for (int i = tid; i < n4; i += T) {
                int4 p = b4[i];
                atomicAdd(&cnt8[g * BUKSZ + (p.x & BUKMASK)], 1);
                atomicAdd(&cnt8[g * BUKSZ + (p.y & BUKMASK)], 1);
                atomicAdd(&cnt8[g * BUKSZ + (p.z & BUKMASK)], 1);
                atomicAdd(&cnt8[g * BUKSZ + (p.w & BUKMASK)], 1);
            }
            if (tid < (n & 3)) atomicAdd(&cnt8[g * BUKSZ + (binned[s0 + (n4 << 2) + tid] & BUKMASK)], 1);
        }
        __syncthreads();
        if (tid < BUKSZ) {
            int v = (b << BUKSHIFT) + tid;
            if (v < N) {
                int cc = 0;
                #pragma unroll
                for (int q = 0; q < 8; ++q) cc += cnt8[q * BUKSZ + tid];
                float d = rsqrtf(1.0f + (float)cc);
                dinv[v] = d;
                y1[v] = d * x[v];
            }
        }
        __syncthreads();
    }
    __threadfence();
    grid.sync();

    // ---------- phase 3: acc1 -> m ----------
    for (int b = bid; b < NBUK; b += NBLK_C) {
        float* acc8 = (float*)stag;   // [8][BUKSZ]
        for (int i = tid; i < 8 * BUKSZ; i += T) acc8[i] = 0.f;
        __syncthreads();
        const int g = tid >> 6;
        for (int sg = 0; sg < NGRP; ++sg) {
            const int s0 = b * CAP + sg * SUBCAP;
            const int n = gofs[(b * NGRP + sg) * GSTRIDE] - s0;
            const int n4 = n >> 2;
            const int4* b4 = (const int4*)(binned + s0);
            for (int i = tid; i < n4; i += T) {
                int4 p = b4[i];
                atomicAdd(&acc8[g * BUKSZ + (p.x & BUKMASK)], y1[p.x >> BUKSHIFT]);
                atomicAdd(&acc8[g * BUKSZ + (p.y & BUKMASK)], y1[p.y >> BUKSHIFT]);
                atomicAdd(&acc8[g * BUKSZ + (p.z & BUKMASK)], y1[p.z >> BUKSHIFT]);
                atomicAdd(&acc8[g * BUKSZ + (p.w & BUKMASK)], y1[p.w >> BUKSHIFT]);
            }
            if (tid < (n & 3)) {
                int p = binned[s0 + (n4 << 2) + tid];
                atomicAdd(&acc8[g * BUKSZ + (p & BUKMASK)], y1[p >> BUKSHIFT]);
            }
        }
        __syncthreads();
        if (tid < BUKSZ) {
            int v = (b << BUKSHIFT) + tid;
            if (v < N) {
                float a = 0.f;
                #pragma unroll
                for (int q = 0; q < 8; ++q) a += acc8[q * BUKSZ + tid];
                float d = dinv[v];
                float s = d * a + d * y1[v];
                m[v] = d * s;
            }
        }
        __syncthreads();
    }
    __threadfence();
    grid.sync();

    // ---------- phase 4: acc2 -> partials ----------
    if (tid < 16) {
        float p = 0.f, q = 0.f;
        for (int k = 0; k < 16; ++k) {
            float w1 = W1[k];
            float w2 = W2[k * 16 + tid];
            p += fmaxf(w1, 0.f) * w2;
            q += fminf(w1, 0.f) * w2;
        }
        sP[tid] = p; sM[tid] = q;
    }
    for (int b = bid; b < NBUK; b += NBLK_C) {
        float* tp = (float*)stag;              // [8][BUKSZ]
        float* tn = (float*)stag + 8 * BUKSZ;  // [8][BUKSZ]
        for (int i = tid; i < 8 * BUKSZ; i += T) { tp[i] = 0.f; tn[i] = 0.f; }
        if (tid < 16) sAcc[tid] = 0.f;
        __syncthreads();
        const int g = tid >> 6;
        for (int sg = 0; sg < NGRP; ++sg) {
            const int s0 = b * CAP + sg * SUBCAP;
            const int n = gofs[(b * NGRP + sg) * GSTRIDE] - s0;
            const int n4 = n >> 2;
            const int4* b4 = (const int4*)(binned + s0);
            for (int i = tid; i < n4; i += T) {
                int4 p = b4[i];
                float v0 = m[p.x >> BUKSHIFT], v1 = m[p.y >> BUKSHIFT];
                float v2 = m[p.z >> BUKSHIFT], v3 = m[p.w >> BUKSHIFT];
                atomicAdd(v0 >= 0.f ? &tp[g * BUKSZ + (p.x & BUKMASK)] : &tn[g * BUKSZ + (p.x & BUKMASK)], v0);
                atomicAdd(v1 >= 0.f ? &tp[g * BUKSZ + (p.y & BUKMASK)] : &tn[g * BUKSZ + (p.y & BUKMASK)], v1);
                atomicAdd(v2 >= 0.f ? &tp[g * BUKSZ + (p.z & BUKMASK)] : &tn[g * BUKSZ + (p.z & BUKMASK)], v2);
                atomicAdd(v3 >= 0.f ? &tp[g * BUKSZ + (p.w & BUKMASK)] : &tn[g * BUKSZ + (p.w & BUKMASK)], v3);
            }
            if (tid < (n & 3)) {
                int p = binned[s0 + (n4 << 2) + tid];
                float val = m[p >> BUKSHIFT];
                atomicAdd(val >= 0.f ? &tp[g * BUKSZ + (p & BUKMASK)] : &tn[g * BUKSZ + (p & BUKMASK)], val);
            }
        }
        __syncthreads();
        float alpha = 0.f, beta = 0.f;
        if (tid < BUKSZ) {
            int v = (b << BUKSHIFT) + tid;
            if (v < N) {
                float a = 0.f, bb = 0.f;
                #pragma unroll
                for (int q = 0; q < 8; ++q) { a += tp[q * BUKSZ + tid]; bb += tn[q * BUKSZ + tid]; }
                float d = dinv[v], mv = m[v];
                alpha = d * a;
                beta  = d * bb;
                float self = d * mv;
                if (mv >= 0.f) alpha += self; else beta += self;
            }
        }
        const int lane = tid & 63;
        for (int j = 0; j < 16; ++j) {
            float h = fmaxf(alpha * sP[j] + beta * sM[j], 0.f);
            #pragma unroll
            for (int off = 32; off > 0; off >>= 1) h += __shfl_down(h, off);
            if (lane == 0 && h != 0.f) atomicAdd(&sAcc[j], h);
        }
        __syncthreads();
        if (tid < 16) partials[b * 16 + tid] = sAcc[tid];
        __syncthreads();
    }
    __threadfence();
    grid.sync();

    // ---------- phase 5: block 0 reduces partials -> out ----------
    if (bid == 0) {
        float* sRed = (float*)stag;   // [32][16]
        const int j = tid & 15;
        const int g = tid >> 4;       // 32 groups
        float acc = 0.f;
        for (int blk = g; blk < NBUK; blk += 32) acc += partials[blk * 16 + j];
        sRed[g * 16 + j] = acc;
        __syncthreads();
        if (tid < 16) {
            float tot = 0.f;
            #pragma unroll
            for (int gg = 0; gg < 32; ++gg) tot += sRed[gg * 16 + tid];
            sRed[tid] = tot * (1.0f / (float)N);
        }
        __syncthreads();
        if (tid < 11) {
            float acc2 = bias[tid];
            #pragma unroll
            for (int k = 0; k < 16; ++k) acc2 += sRed[k] * W3[k * 11 + tid];
            out[tid] = acc2;
        }
    }
}

// ===================== fallback multi-kernel path (proven R5) =====================
__global__ void k_init(int* __restrict__ gofs) {
    int i = blockIdx.x * blockDim.x + threadIdx.x;
    if (i < NBUK * NGRP) {
        int b = i / NGRP, g = i % NGRP;
        gofs[i * GSTRIDE] = b * CAP + g * SUBCAP;
    }
}

__global__ __launch_bounds__(1024) void k_scatter(const int4* __restrict__ rows4,
                                                  const int4* __restrict__ cols4,
                                                  int* __restrict__ gofs,
                                                  int* __restrict__ binned) {
    __shared__ int hist[4][NBUK];
    __shared__ int cnt[512];
    __shared__ int lbase[NBUK];
    __shared__ int gbase[NBUK];
    __shared__ int stag[SC_CHUNK];

    const int tid = threadIdx.x;
    const int g = tid >> 8;
    const int grp = blockIdx.x & (NGRP - 1);
    for (int i = tid; i < 4 * NBUK; i += 1024) (&hist[0][0])[i] = 0;
    if (tid < 512) cnt[tid] = 0;
    __syncthreads();

    const int nI4 = E / 4;
    const int base4 = blockIdx.x * (SC_CHUNK / 4);
    const int ia = base4 + tid, ib = base4 + 1024 + tid;
    const bool va = ia < nI4, vb = ib < nI4;
    int4 ra, ca, rb, cb;
    if (va) { ra = rows4[ia]; ca = cols4[ia]; }
    if (vb) { rb = rows4[ib]; cb = cols4[ib]; }

    if (va) {
        atomicAdd(&hist[g][ca.x >> BUKSHIFT], 1);
        atomicAdd(&hist[g][ca.y >> BUKSHIFT], 1);
        atomicAdd(&hist[g][ca.z >> BUKSHIFT], 1);
        atomicAdd(&hist[g][ca.w >> BUKSHIFT], 1);
    }
    if (vb) {
        atomicAdd(&hist[g][cb.x >> BUKSHIFT], 1);
        atomicAdd(&hist[g][cb.y >> BUKSHIFT], 1);
        atomicAdd(&hist[g][cb.z >> BUKSHIFT], 1);
        atomicAdd(&hist[g][cb.w >> BUKSHIFT], 1);
    }
    __syncthreads();

    if (tid < NBUK) {
        int h0 = hist[0][tid], h1 = hist[1][tid], h2 = hist[2][tid], h3 = hist[3][tid];
        hist[0][tid] = 0; hist[1][tid] = h0; hist[2][tid] = h0 + h1; hist[3][tid] = h0 + h1 + h2;
        int c = h0 + h1 + h2 + h3;
        cnt[tid] = c;
        gbase[tid] = c ? atomicAdd(&gofs[(tid * NGRP + grp) * GSTRIDE], c) : 0;
    }
    __syncthreads();
    for (int off = 1; off < 512; off <<= 1) {
        int v = 0;
        if (tid < 512) { v = cnt[tid]; if (tid >= off) v += cnt[tid - off]; }
        __syncthreads();
        if (tid < 512) cnt[tid] = v;
        __syncthreads();
    }
    if (tid < NBUK) lbase[tid] = tid ? cnt[tid - 1] : 0;
    __syncthreads();

    if (va) {
        int b, off;
        b = ca.x >> BUKSHIFT; off = atomicAdd(&hist[g][b], 1); stag[lbase[b] + off] = (ra.x << BUKSHIFT) | (ca.x & BUKMASK);
        b = ca.y >> BUKSHIFT; off = atomicAdd(&hist[g][b], 1); stag[lbase[b] + off] = (ra.y << BUKSHIFT) | (ca.y & BUKMASK);
        b = ca.z >> BUKSHIFT; off = atomicAdd(&hist[g][b], 1); stag[lbase[b] + off] = (ra.z << BUKSHIFT) | (ca.z & BUKMASK);
        b = ca.w >> BUKSHIFT; off = atomicAdd(&hist[g][b], 1); stag[lbase[b] + off] = (ra.w << BUKSHIFT) | (ca.w & BUKMASK);
    }
    if (vb) {
        int b, off;
        b = cb.x >> BUKSHIFT; off = atomicAdd(&hist[g][b], 1); stag[lbase[b] + off] = (rb.x << BUKSHIFT) | (cb.x & BUKMASK);
        b = cb.y >> BUKSHIFT; off = atomicAdd(&hist[g][b], 1); stag[lbase[b] + off] = (rb.y << BUKSHIFT) | (cb.y & BUKMASK);
        b = cb.z >> BUKSHIFT; off = atomicAdd(&hist[g][b], 1); stag[lbase[b] + off] = (rb.z << BUKSHIFT) | (cb.z & BUKMASK);
        b = cb.w >> BUKSHIFT; off = atomicAdd(&hist[g][b], 1); stag[lbase[b] + off] = (rb.w << BUKSHIFT) | (cb.w & BUKMASK);
    }
    __syncthreads();

    const int eTot = min(SC_CHUNK, E - blockIdx.x * SC_CHUNK);
    int s = tid * 8;
    if (s < eTot) {
        int lo = 0, hi = NBUK - 1;
        while (lo < hi) { int mid = (lo + hi + 1) >> 1; if (lbase[mid] <= s) lo = mid; else hi = mid - 1; }
        int b = lo;
        const int e1 = min(s + 8, eTot);
        for (; s < e1; ++s) {
            while (b + 1 < NBUK && lbase[b + 1] <= s) ++b;
            binned[gbase[b] + (s - lbase[b])] = stag[s];
        }
    }
}

__global__ __launch_bounds__(1024) void k_deg(const int* __restrict__ binned,
                                              const int* __restrict__ gofs,
                                              const float* __restrict__ x,
                                              float* __restrict__ dinv,
                                              float* __restrict__ y1) {
    __shared__ int cnt[8][BUKSZ];
    const int tid = threadIdx.x;
    for (int i = tid; i < 8 * BUKSZ; i += 1024) (&cnt[0][0])[i] = 0;
    __syncthreads();
    const int b = blockIdx.x, g = tid >> 7;
    for (int sg = 0; sg < NGRP; ++sg) {
        const int s0 = b * CAP + sg * SUBCAP;
        const int n = gofs[(b * NGRP + sg) * GSTRIDE] - s0;
        const int n4 = n >> 2;
        const int4* b4 = (const int4*)(binned + s0);
        for (int i = tid; i < n4; i += 1024) {
            int4 p = b4[i];
            atomicAdd(&cnt[g][p.x & BUKMASK], 1);
            atomicAdd(&cnt[g][p.y & BUKMASK], 1);
            atomicAdd(&cnt[g][p.z & BUKMASK], 1);
            atomicAdd(&cnt[g][p.w & BUKMASK], 1);
        }
        if (tid < (n & 3)) atomicAdd(&cnt[g][binned[s0 + (n4 << 2) + tid] & BUKMASK], 1);
    }
    __syncthreads();
    if (tid < BUKSZ) {
        int v = (b << BUKSHIFT) + tid;
        if (v < N) {
            int c = 0;
            #pragma unroll
            for (int q = 0; q < 8; ++q) c += cnt[q][tid];
            float d = rsqrtf(1.0f + (float)c);
            dinv[v] = d;
            y1[v] = d * x[v];
        }
    }
}

__global__ __launch_bounds__(1024) void k_acc1(const int* __restrict__ binned,
                                               const int* __restrict__ gofs,
                                               const float* __restrict__ y1,
                                               const float* __restrict__ dinv,
                                               float* __restrict__ m) {
    __shared__ float acc[8][BUKSZ];
    const int tid = threadIdx.x;
    for (int i = tid; i < 8 * BUKSZ; i += 1024) (&acc[0][0])[i] = 0.f;
    __syncthreads();
    const int b = blockIdx.x, g = tid >> 7;
    for (int sg = 0; sg < NGRP; ++sg) {
        const int s0 = b * CAP + sg * SUBCAP;
        const int n = gofs[(b * NGRP + sg) * GSTRIDE] - s0;
        const int n4 = n >> 2;
        const int4* b4 = (const int4*)(binned + s0);
        for (int i = tid; i < n4; i += 1024) {
            int4 p = b4[i];
            atomicAdd(&acc[g][p.x & BUKMASK], y1[p.x >> BUKSHIFT]);
            atomicAdd(&acc[g][p.y & BUKMASK], y1[p.y >> BUKSHIFT]);
            atomicAdd(&acc[g][p.z & BUKMASK], y1[p.z >> BUKSHIFT]);
            atomicAdd(&acc[g][p.w & BUKMASK], y1[p.w >> BUKSHIFT]);
        }
        if (tid < (n & 3)) {
            int p = binned[s0 + (n4 << 2) + tid];
            atomicAdd(&acc[g][p & BUKMASK], y1[p >> BUKSHIFT]);
        }
    }
    __syncthreads();
    if (tid < BUKSZ) {
        int v = (b << BUKSHIFT) + tid;
        if (v < N) {
            float a = 0.f;
            #pragma unroll
            for (int q = 0; q < 8; ++q) a += acc[q][tid];
            float d = dinv[v];
            float s = d * a + d * y1[v];
            m[v] = d * s;
        }
    }
}

__global__ __launch_bounds__(1024) void k_acc2(const int* __restrict__ binned,
                                               const int* __restrict__ gofs,
                                               const float* __restrict__ m,
                                               const float* __restrict__ dinv,
                                               const float* __restrict__ W1,
                                               const float* __restrict__ W2,
                                               float* __restrict__ partials) {
    __shared__ float tp[8][BUKSZ], tn[8][BUKSZ];
    __shared__ float sP[16], sM[16], sAcc[16];
    const int tid = threadIdx.x;
    if (tid < 16) {
        float p = 0.f, q = 0.f;
        for (int k = 0; k < 16; ++k) {
            float w1 = W1[k];
            float w2 = W2[k * 16 + tid];
            p += fmaxf(w1, 0.f) * w2;
            q += fminf(w1, 0.f) * w2;
        }
        sP[tid] = p; sM[tid] = q; sAcc[tid] = 0.f;
    }
    for (int i = tid; i < 8 * BUKSZ; i += 1024) { (&tp[0][0])[i] = 0.f; (&tn[0][0])[i] = 0.f; }
    __syncthreads();
    const int b = blockIdx.x, g = tid >> 7;
    for (int sg = 0; sg < NGRP; ++sg) {
        const int s0 = b * CAP + sg * SUBCAP;
        const int n = gofs[(b * NGRP + sg) * GSTRIDE] - s0;
        const int n4 = n >> 2;
        const int4* b4 = (const int4*)(binned + s0);
        for (int i = tid; i < n4; i += 1024) {
            int4 p = b4[i];
            float v0 = m[p.x >> BUKSHIFT], v1 = m[p.y >> BUKSHIFT];
            float v2 = m[p.z >> BUKSHIFT], v3 = m[p.w >> BUKSHIFT];
            atomicAdd(v0 >= 0.f ? &tp[g][p.x & BUKMASK] : &tn[g][p.x & BUKMASK], v0);
            atomicAdd(v1 >= 0.f ? &tp[g][p.y & BUKMASK] : &tn[g][p.y & BUKMASK], v1);
            atomicAdd(v2 >= 0.f ? &tp[g][p.z & BUKMASK] : &tn[g][p.z & BUKMASK], v2);
            atomicAdd(v3 >= 0.f ? &tp[g][p.w & BUKMASK] : &tn[g][p.w & BUKMASK], v3);
        }
        if (tid < (n & 3)) {
            int p = binned[s0 + (n4 << 2) + tid];
            float val = m[p >> BUKSHIFT];
            atomicAdd(val >= 0.f ? &tp[g][p & BUKMASK] : &tn[g][p & BUKMASK], val);
        }
    }
    __syncthreads();
    float alpha = 0.f, beta = 0.f;
    if (tid < BUKSZ) {
        int v = (b << BUKSHIFT) + tid;
        if (v < N) {
            float a = 0.f, bb = 0.f;
            #pragma unroll
            for (int q = 0; q < 8; ++q) { a += tp[q][tid]; bb += tn[q][tid]; }
            float d = dinv[v], mv = m[v];
            alpha = d * a;
            beta  = d * bb;
            float self = d * mv;
            if (mv >= 0.f) alpha += self; else beta += self;
        }
    }
    const int lane = tid & 63;
    for (int j = 0; j < 16; ++j) {
        float h = fmaxf(alpha * sP[j] + beta * sM[j], 0.f);
        #pragma unroll
        for (int off = 32; off > 0; off >>= 1) h += __shfl_down(h, off);
        if (lane == 0 && h != 0.f) atomicAdd(&sAcc[j], h);
    }
    __syncthreads();
    if (tid < 16) partials[b * 16 + tid] = sAcc[tid];
}

__global__ void k_out(const float* __restrict__ partials, const float* __restrict__ W3,
                      const float* __restrict__ b, float* __restrict__ out) {
    __shared__ float s[16][16];
    int j = threadIdx.x & 15;
    int g = threadIdx.x >> 4;
    float acc = 0.f;
    for (int blk = g; blk < NBUK; blk += 16) acc += partials[blk * 16 + j];
    s[g][j] = acc;
    __syncthreads();
    if (threadIdx.x < 16) {
        float tot = 0.f;
        #pragma unroll
        for (int gg = 0; gg < 16; ++gg) tot += s[gg][threadIdx.x];
        s[0][threadIdx.x] = tot * (1.0f / (float)N);
    }
    __syncthreads();
    if (threadIdx.x < 11) {
        float acc2 = b[threadIdx.x];
        #pragma unroll
        for (int k = 0; k < 16; ++k) acc2 += s[0][k] * W3[k * 11 + threadIdx.x];
        out[threadIdx.x] = acc2;
    }
}

extern "C" void kernel_launch(void* const* d_in, const int* in_sizes, int n_in,
                              void* d_out, int out_size, void* d_ws, size_t ws_size,
                              hipStream_t stream) {
    const float* x  = (const float*)d_in[0];
    const int*   ei = (const int*)d_in[1];   // [2*E]: rows then cols (int32)
    const float* W1 = (const float*)d_in[2];
    const float* W2 = (const float*)d_in[3];
    const float* W3 = (const float*)d_in[4];
    const float* b  = (const float*)d_in[5];
    float* out = (float*)d_out;

    int*   wsi      = (int*)d_ws;
    int*   binned   = wsi;                                      // NBUK*CAP
    float* dinv     = (float*)(wsi + (size_t)NBUK * CAP);
    float* y1       = dinv + N;
    float* m        = y1 + N;
    int*   gofs     = (int*)(m + N);                            // NBUK*NGRP*GSTRIDE
    float* partials = (float*)(gofs + NBUK * NGRP * GSTRIDE);   // NBUK*16

    const int4* rows4 = (const int4*)ei;
    const int4* cols4 = (const int4*)(ei + E);

    void* args[] = { (void*)&rows4, (void*)&cols4, (void*)&x, (void*)&W1, (void*)&W2,
                     (void*)&W3, (void*)&b, (void*)&binned, (void*)&gofs, (void*)&dinv,
                     (void*)&y1, (void*)&m, (void*)&partials, (void*)&out };
    hipError_t err = hipLaunchCooperativeKernel((const void*)k_fused, dim3(NBLK_C), dim3(T),
                                                args, 0, stream);
    if (err != hipSuccess) {
        // deterministic fallback: proven multi-kernel path
        k_init   <<<(NBUK * NGRP + 511) / 512, 512, 0, stream>>>(gofs);
        k_scatter<<<NCHUNK, 1024, 0, stream>>>(rows4, cols4, gofs, binned);
        k_deg    <<<NBUK, 1024, 0, stream>>>(binned, gofs, x, dinv, y1);
        k_acc1   <<<NBUK, 1024, 0, stream>>>(binned, gofs, y1, dinv, m);
        k_acc2   <<<NBUK, 1024, 0, stream>>>(binned, gofs, m, dinv, W1, W2, partials);
        k_out    <<<1, 256, 0, stream>>>(partials, W3, b, out);
    }
}

// Round 9
// 119.190 us; speedup vs baseline: 3.9434x; 3.9434x over previous
//
#include <hip/hip_runtime.h>

static constexpr int N = 100000;
static constexpr int E = 3200000;
static constexpr int BUKSHIFT = 8;
static constexpr int BUKSZ = 1 << BUKSHIFT;             // 256 nodes / bucket
static constexpr int BUKMASK = BUKSZ - 1;
static constexpr int NBUK = (N + BUKSZ - 1) / BUKSZ;    // 391
static constexpr int NGRP = 8;                           // reservation groups
static constexpr int SUBCAP = 1536;                      // slots per (bucket,group)
static constexpr int CAP = NGRP * SUBCAP;                // 12288 per bucket
static constexpr int GSTRIDE = 16;                       // pad counters to 64B lines
static constexpr int SC_CHUNK = 4096;
static constexpr int SC_T = 512;
static constexpr int SC_BLOCKS = (E + SC_CHUNK - 1) / SC_CHUNK;  // 782

// ws (4B): binned[NBUK*CAP] | dinv[N] | y1[N] | m[N] | gofs[NBUK*NGRP*GSTRIDE] (counts) | partials[NBUK*16]

// Block-local counting sort of 4096 edges by destination bucket, then
// coalesced-run writes into this block's group sub-segment. gofs = counts.
__global__ __launch_bounds__(SC_T) void k_scatter(const int4* __restrict__ rows4,
                                                  const int4* __restrict__ cols4,
                                                  int* __restrict__ gofs,
                                                  int* __restrict__ binned) {
    __shared__ int hist[2 * NBUK];   // 2 replica hists -> replica-exclusive bases
    __shared__ int cnt[512];
    __shared__ int lbase[NBUK];
    __shared__ int gbase[NBUK];
    __shared__ int stag[SC_CHUNK];

    const int tid = threadIdx.x;
    const int g = tid >> 8;          // 2 replica groups
    const int grp = blockIdx.x & (NGRP - 1);
    for (int i = tid; i < 2 * NBUK; i += SC_T) hist[i] = 0;
    cnt[tid] = 0;
    __syncthreads();

    const int nI4 = E / 4;
    const int base4 = blockIdx.x * (SC_CHUNK / 4);
    const int ia = base4 + tid, ib = base4 + SC_T + tid;
    const bool va = ia < nI4, vb = ib < nI4;
    int4 ra, ca, rb, cb;
    if (va) { ra = rows4[ia]; ca = cols4[ia]; }
    if (vb) { rb = rows4[ib]; cb = cols4[ib]; }

    if (va) {
        atomicAdd(&hist[g * NBUK + (ca.x >> BUKSHIFT)], 1);
        atomicAdd(&hist[g * NBUK + (ca.y >> BUKSHIFT)], 1);
        atomicAdd(&hist[g * NBUK + (ca.z >> BUKSHIFT)], 1);
        atomicAdd(&hist[g * NBUK + (ca.w >> BUKSHIFT)], 1);
    }
    if (vb) {
        atomicAdd(&hist[g * NBUK + (cb.x >> BUKSHIFT)], 1);
        atomicAdd(&hist[g * NBUK + (cb.y >> BUKSHIFT)], 1);
        atomicAdd(&hist[g * NBUK + (cb.z >> BUKSHIFT)], 1);
        atomicAdd(&hist[g * NBUK + (cb.w >> BUKSHIFT)], 1);
    }
    __syncthreads();

    if (tid < NBUK) {
        int h0 = hist[0 * NBUK + tid], h1 = hist[1 * NBUK + tid];
        hist[0 * NBUK + tid] = 0;
        hist[1 * NBUK + tid] = h0;
        int c = h0 + h1;
        cnt[tid] = c;
        int off = c ? atomicAdd(&gofs[(tid * NGRP + grp) * GSTRIDE], c) : 0;
        gbase[tid] = tid * CAP + grp * SUBCAP + off;
    }
    __syncthreads();
    for (int off = 1; off < 512; off <<= 1) {
        int v = cnt[tid];
        if (tid >= off) v += cnt[tid - off];
        __syncthreads();
        cnt[tid] = v;
        __syncthreads();
    }
    if (tid < NBUK) lbase[tid] = tid ? cnt[tid - 1] : 0;
    __syncthreads();

    if (va) {
        int b, off;
        b = ca.x >> BUKSHIFT; off = atomicAdd(&hist[g * NBUK + b], 1); stag[lbase[b] + off] = (ra.x << BUKSHIFT) | (ca.x & BUKMASK);
        b = ca.y >> BUKSHIFT; off = atomicAdd(&hist[g * NBUK + b], 1); stag[lbase[b] + off] = (ra.y << BUKSHIFT) | (ca.y & BUKMASK);
        b = ca.z >> BUKSHIFT; off = atomicAdd(&hist[g * NBUK + b], 1); stag[lbase[b] + off] = (ra.z << BUKSHIFT) | (ca.z & BUKMASK);
        b = ca.w >> BUKSHIFT; off = atomicAdd(&hist[g * NBUK + b], 1); stag[lbase[b] + off] = (ra.w << BUKSHIFT) | (ca.w & BUKMASK);
    }
    if (vb) {
        int b, off;
        b = cb.x >> BUKSHIFT; off = atomicAdd(&hist[g * NBUK + b], 1); stag[lbase[b] + off] = (rb.x << BUKSHIFT) | (cb.x & BUKMASK);
        b = cb.y >> BUKSHIFT; off = atomicAdd(&hist[g * NBUK + b], 1); stag[lbase[b] + off] = (rb.y << BUKSHIFT) | (cb.y & BUKMASK);
        b = cb.z >> BUKSHIFT; off = atomicAdd(&hist[g * NBUK + b], 1); stag[lbase[b] + off] = (rb.z << BUKSHIFT) | (cb.z & BUKMASK);
        b = cb.w >> BUKSHIFT; off = atomicAdd(&hist[g * NBUK + b], 1); stag[lbase[b] + off] = (rb.w << BUKSHIFT) | (cb.w & BUKMASK);
    }
    __syncthreads();

    const int eTot = min(SC_CHUNK, E - blockIdx.x * SC_CHUNK);
    int s = tid * 8;
    if (s < eTot) {
        int lo = 0, hi = NBUK - 1;
        while (lo < hi) { int mid = (lo + hi + 1) >> 1; if (lbase[mid] <= s) lo = mid; else hi = mid - 1; }
        int b = lo;
        const int e1 = min(s + 8, eTot);
        for (; s < e1; ++s) {
            while (b + 1 < NBUK && lbase[b + 1] <= s) ++b;
            binned[gbase[b] + (s - lbase[b])] = stag[s];
        }
    }
}

// per-bucket degree -> dinv, y1
__global__ __launch_bounds__(1024) void k_deg(const int* __restrict__ binned,
                                              const int* __restrict__ gofs,
                                              const float* __restrict__ x,
                                              float* __restrict__ dinv,
                                              float* __restrict__ y1) {
    __shared__ int cnt[8][BUKSZ];
    const int tid = threadIdx.x;
    for (int i = tid; i < 8 * BUKSZ; i += 1024) (&cnt[0][0])[i] = 0;
    __syncthreads();
    const int b = blockIdx.x, g = tid >> 7;
    for (int sg = 0; sg < NGRP; ++sg) {
        const int s0 = b * CAP + sg * SUBCAP;
        const int n = gofs[(b * NGRP + sg) * GSTRIDE];
        const int n4 = n >> 2;
        const int4* b4 = (const int4*)(binned + s0);
        for (int i = tid; i < n4; i += 1024) {
            int4 p = b4[i];
            atomicAdd(&cnt[g][p.x & BUKMASK], 1);
            atomicAdd(&cnt[g][p.y & BUKMASK], 1);
            atomicAdd(&cnt[g][p.z & BUKMASK], 1);
            atomicAdd(&cnt[g][p.w & BUKMASK], 1);
        }
        if (tid < (n & 3)) atomicAdd(&cnt[g][binned[s0 + (n4 << 2) + tid] & BUKMASK], 1);
    }
    __syncthreads();
    if (tid < BUKSZ) {
        int v = (b << BUKSHIFT) + tid;
        if (v < N) {
            int c = 0;
            #pragma unroll
            for (int q = 0; q < 8; ++q) c += cnt[q][tid];
            float d = rsqrtf(1.0f + (float)c);
            dinv[v] = d;
            y1[v] = d * x[v];
        }
    }
}

// per-bucket acc1 -> m
__global__ __launch_bounds__(1024) void k_acc1(const int* __restrict__ binned,
                                               const int* __restrict__ gofs,
                                               const float* __restrict__ y1,
                                               const float* __restrict__ dinv,
                                               float* __restrict__ m) {
    __shared__ float acc[8][BUKSZ];
    const int tid = threadIdx.x;
    for (int i = tid; i < 8 * BUKSZ; i += 1024) (&acc[0][0])[i] = 0.f;
    __syncthreads();
    const int b = blockIdx.x, g = tid >> 7;
    for (int sg = 0; sg < NGRP; ++sg) {
        const int s0 = b * CAP + sg * SUBCAP;
        const int n = gofs[(b * NGRP + sg) * GSTRIDE];
        const int n4 = n >> 2;
        const int4* b4 = (const int4*)(binned + s0);
        for (int i = tid; i < n4; i += 1024) {
            int4 p = b4[i];
            atomicAdd(&acc[g][p.x & BUKMASK], y1[p.x >> BUKSHIFT]);
            atomicAdd(&acc[g][p.y & BUKMASK], y1[p.y >> BUKSHIFT]);
            atomicAdd(&acc[g][p.z & BUKMASK], y1[p.z >> BUKSHIFT]);
            atomicAdd(&acc[g][p.w & BUKMASK], y1[p.w >> BUKSHIFT]);
        }
        if (tid < (n & 3)) {
            int p = binned[s0 + (n4 << 2) + tid];
            atomicAdd(&acc[g][p & BUKMASK], y1[p >> BUKSHIFT]);
        }
    }
    __syncthreads();
    if (tid < BUKSZ) {
        int v = (b << BUKSHIFT) + tid;
        if (v < N) {
            float a = 0.f;
            #pragma unroll
            for (int q = 0; q < 8; ++q) a += acc[q][tid];
            float d = dinv[v];
            float s = d * a + d * y1[v];
            m[v] = d * s;
        }
    }
}

// per-bucket tpos/tneg -> h2 -> per-block partial column sums
__global__ __launch_bounds__(1024) void k_acc2(const int* __restrict__ binned,
                                               const int* __restrict__ gofs,
                                               const float* __restrict__ m,
                                               const float* __restrict__ dinv,
                                               const float* __restrict__ W1,
                                               const float* __restrict__ W2,
                                               float* __restrict__ partials) {
    __shared__ float tp[8][BUKSZ], tn[8][BUKSZ];
    __shared__ float sP[16], sM[16], sAcc[16];
    const int tid = threadIdx.x;
    if (tid < 16) {
        float p = 0.f, q = 0.f;
        for (int k = 0; k < 16; ++k) {
            float w1 = W1[k];
            float w2 = W2[k * 16 + tid];
            p += fmaxf(w1, 0.f) * w2;
            q += fminf(w1, 0.f) * w2;
        }
        sP[tid] = p; sM[tid] = q; sAcc[tid] = 0.f;
    }
    for (int i = tid; i < 8 * BUKSZ; i += 1024) { (&tp[0][0])[i] = 0.f; (&tn[0][0])[i] = 0.f; }
    __syncthreads();
    const int b = blockIdx.x, g = tid >> 7;
    for (int sg = 0; sg < NGRP; ++sg) {
        const int s0 = b * CAP + sg * SUBCAP;
        const int n = gofs[(b * NGRP + sg) * GSTRIDE];
        const int n4 = n >> 2;
        const int4* b4 = (const int4*)(binned + s0);
        for (int i = tid; i < n4; i += 1024) {
            int4 p = b4[i];
            float v0 = m[p.x >> BUKSHIFT], v1 = m[p.y >> BUKSHIFT];
            float v2 = m[p.z >> BUKSHIFT], v3 = m[p.w >> BUKSHIFT];
            atomicAdd(v0 >= 0.f ? &tp[g][p.x & BUKMASK] : &tn[g][p.x & BUKMASK], v0);
            atomicAdd(v1 >= 0.f ? &tp[g][p.y & BUKMASK] : &tn[g][p.y & BUKMASK], v1);
            atomicAdd(v2 >= 0.f ? &tp[g][p.z & BUKMASK] : &tn[g][p.z & BUKMASK], v2);
            atomicAdd(v3 >= 0.f ? &tp[g][p.w & BUKMASK] : &tn[g][p.w & BUKMASK], v3);
        }
        if (tid < (n & 3)) {
            int p = binned[s0 + (n4 << 2) + tid];
            float val = m[p >> BUKSHIFT];
            atomicAdd(val >= 0.f ? &tp[g][p & BUKMASK] : &tn[g][p & BUKMASK], val);
        }
    }
    __syncthreads();
    float alpha = 0.f, beta = 0.f;
    if (tid < BUKSZ) {
        int v = (b << BUKSHIFT) + tid;
        if (v < N) {
            float a = 0.f, bb = 0.f;
            #pragma unroll
            for (int q = 0; q < 8; ++q) { a += tp[q][tid]; bb += tn[q][tid]; }
            float d = dinv[v], mv = m[v];
            alpha = d * a;
            beta  = d * bb;
            float self = d * mv;
            if (mv >= 0.f) alpha += self; else beta += self;
        }
    }
    const int lane = tid & 63;
    for (int j = 0; j < 16; ++j) {
        float h = fmaxf(alpha * sP[j] + beta * sM[j], 0.f);
        #pragma unroll
        for (int off = 32; off > 0; off >>= 1) h += __shfl_down(h, off);
        if (lane == 0 && h != 0.f) atomicAdd(&sAcc[j], h);
    }
    __syncthreads();
    if (tid < 16) partials[b * 16 + tid] = sAcc[tid];
}

// reduce partials[NBUK][16] -> mean -> out = g @ W3 + b
__global__ void k_out(const float* __restrict__ partials, const float* __restrict__ W3,
                      const float* __restrict__ b, float* __restrict__ out) {
    __shared__ float s[16][16];
    int j = threadIdx.x & 15;
    int g = threadIdx.x >> 4;
    float acc = 0.f;
    for (int blk = g; blk < NBUK; blk += 16) acc += partials[blk * 16 + j];
    s[g][j] = acc;
    __syncthreads();
    if (threadIdx.x < 16) {
        float tot = 0.f;
        #pragma unroll
        for (int gg = 0; gg < 16; ++gg) tot += s[gg][threadIdx.x];
        s[0][threadIdx.x] = tot * (1.0f / (float)N);
    }
    __syncthreads();
    if (threadIdx.x < 11) {
        float acc2 = b[threadIdx.x];
        #pragma unroll
        for (int k = 0; k < 16; ++k) acc2 += s[0][k] * W3[k * 11 + threadIdx.x];
        out[threadIdx.x] = acc2;
    }
}

extern "C" void kernel_launch(void* const* d_in, const int* in_sizes, int n_in,
                              void* d_out, int out_size, void* d_ws, size_t ws_size,
                              hipStream_t stream) {
    const float* x  = (const float*)d_in[0];
    const int*   ei = (const int*)d_in[1];   // [2*E]: rows then cols (int32)
    const float* W1 = (const float*)d_in[2];
    const float* W2 = (const float*)d_in[3];
    const float* W3 = (const float*)d_in[4];
    const float* b  = (const float*)d_in[5];
    float* out = (float*)d_out;

    int*   wsi      = (int*)d_ws;
    int*   binned   = wsi;                                      // NBUK*CAP
    float* dinv     = (float*)(wsi + (size_t)NBUK * CAP);
    float* y1       = dinv + N;
    float* m        = y1 + N;
    int*   gofs     = (int*)(m + N);                            // NBUK*NGRP*GSTRIDE (counts)
    float* partials = (float*)(gofs + NBUK * NGRP * GSTRIDE);   // NBUK*16

    const int4* rows4 = (const int4*)ei;
    const int4* cols4 = (const int4*)(ei + E);

    hipMemsetAsync(gofs, 0, (size_t)NBUK * NGRP * GSTRIDE * sizeof(int), stream);
    k_scatter<<<SC_BLOCKS, SC_T, 0, stream>>>(rows4, cols4, gofs, binned);
    k_deg    <<<NBUK, 1024, 0, stream>>>(binned, gofs, x, dinv, y1);
    k_acc1   <<<NBUK, 1024, 0, stream>>>(binned, gofs, y1, dinv, m);
    k_acc2   <<<NBUK, 1024, 0, stream>>>(binned, gofs, m, dinv, W1, W2, partials);
    k_out    <<<1, 256, 0, stream>>>(partials, W3, b, out);
}

// Round 10
// 118.146 us; speedup vs baseline: 3.9782x; 1.0088x over previous
//
#include <hip/hip_runtime.h>

static constexpr int N = 100000;
static constexpr int E = 3200000;
static constexpr int BUKSHIFT = 8;
static constexpr int BUKSZ = 1 << BUKSHIFT;             // 256 nodes / bucket
static constexpr int BUKMASK = BUKSZ - 1;
static constexpr int NBUK = (N + BUKSZ - 1) / BUKSZ;    // 391
static constexpr int NGRP = 8;                           // reservation groups
static constexpr int SUBCAP = 1536;                      // slots per (bucket,group)
static constexpr int CAP = NGRP * SUBCAP;                // 12288 per bucket
static constexpr int GSTRIDE = 16;                       // pad counters to 64B lines
static constexpr int SC_CHUNK = 4096;
static constexpr int SC_T = 512;
static constexpr int SC_BLOCKS = (E + SC_CHUNK - 1) / SC_CHUNK;  // 782

// ws (4B): binned[NBUK*CAP] | dinv[N] | y1[N] | m[N] | gofs[NBUK*NGRP*GSTRIDE] (counts) | partials[NBUK*16]

__global__ void k_init(int* __restrict__ gofs) {
    int i = blockIdx.x * blockDim.x + threadIdx.x;
    if (i < NBUK * NGRP) gofs[i * GSTRIDE] = 0;
}

// Block-local counting sort of 4096 edges by destination bucket, then
// coalesced-run writes into this block's group sub-segment. gofs = counts.
__global__ __launch_bounds__(SC_T) void k_scatter(const int4* __restrict__ rows4,
                                                  const int4* __restrict__ cols4,
                                                  int* __restrict__ gofs,
                                                  int* __restrict__ binned) {
    __shared__ int hist[2 * NBUK];   // 2 replica hists -> replica-exclusive bases
    __shared__ int cnt[512];
    __shared__ int lbase[NBUK];
    __shared__ int gbase[NBUK];
    __shared__ int stag[SC_CHUNK];

    const int tid = threadIdx.x;
    const int g = tid >> 8;          // 2 replica groups
    const int grp = blockIdx.x & (NGRP - 1);
    for (int i = tid; i < 2 * NBUK; i += SC_T) hist[i] = 0;
    cnt[tid] = 0;
    __syncthreads();

    const int nI4 = E / 4;
    const int base4 = blockIdx.x * (SC_CHUNK / 4);
    const int ia = base4 + tid, ib = base4 + SC_T + tid;
    const bool va = ia < nI4, vb = ib < nI4;
    int4 ra, ca, rb, cb;
    if (va) { ra = rows4[ia]; ca = cols4[ia]; }
    if (vb) { rb = rows4[ib]; cb = cols4[ib]; }

    if (va) {
        atomicAdd(&hist[g * NBUK + (ca.x >> BUKSHIFT)], 1);
        atomicAdd(&hist[g * NBUK + (ca.y >> BUKSHIFT)], 1);
        atomicAdd(&hist[g * NBUK + (ca.z >> BUKSHIFT)], 1);
        atomicAdd(&hist[g * NBUK + (ca.w >> BUKSHIFT)], 1);
    }
    if (vb) {
        atomicAdd(&hist[g * NBUK + (cb.x >> BUKSHIFT)], 1);
        atomicAdd(&hist[g * NBUK + (cb.y >> BUKSHIFT)], 1);
        atomicAdd(&hist[g * NBUK + (cb.z >> BUKSHIFT)], 1);
        atomicAdd(&hist[g * NBUK + (cb.w >> BUKSHIFT)], 1);
    }
    __syncthreads();

    if (tid < NBUK) {
        int h0 = hist[0 * NBUK + tid], h1 = hist[1 * NBUK + tid];
        hist[0 * NBUK + tid] = 0;
        hist[1 * NBUK + tid] = h0;
        int c = h0 + h1;
        cnt[tid] = c;
        int off = c ? atomicAdd(&gofs[(tid * NGRP + grp) * GSTRIDE], c) : 0;
        gbase[tid] = tid * CAP + grp * SUBCAP + off;
    }
    __syncthreads();
    for (int off = 1; off < 512; off <<= 1) {
        int v = cnt[tid];
        if (tid >= off) v += cnt[tid - off];
        __syncthreads();
        cnt[tid] = v;
        __syncthreads();
    }
    if (tid < NBUK) lbase[tid] = tid ? cnt[tid - 1] : 0;
    __syncthreads();

    if (va) {
        int b, off;
        b = ca.x >> BUKSHIFT; off = atomicAdd(&hist[g * NBUK + b], 1); stag[lbase[b] + off] = (ra.x << BUKSHIFT) | (ca.x & BUKMASK);
        b = ca.y >> BUKSHIFT; off = atomicAdd(&hist[g * NBUK + b], 1); stag[lbase[b] + off] = (ra.y << BUKSHIFT) | (ca.y & BUKMASK);
        b = ca.z >> BUKSHIFT; off = atomicAdd(&hist[g * NBUK + b], 1); stag[lbase[b] + off] = (ra.z << BUKSHIFT) | (ca.z & BUKMASK);
        b = ca.w >> BUKSHIFT; off = atomicAdd(&hist[g * NBUK + b], 1); stag[lbase[b] + off] = (ra.w << BUKSHIFT) | (ca.w & BUKMASK);
    }
    if (vb) {
        int b, off;
        b = cb.x >> BUKSHIFT; off = atomicAdd(&hist[g * NBUK + b], 1); stag[lbase[b] + off] = (rb.x << BUKSHIFT) | (cb.x & BUKMASK);
        b = cb.y >> BUKSHIFT; off = atomicAdd(&hist[g * NBUK + b], 1); stag[lbase[b] + off] = (rb.y << BUKSHIFT) | (cb.y & BUKMASK);
        b = cb.z >> BUKSHIFT; off = atomicAdd(&hist[g * NBUK + b], 1); stag[lbase[b] + off] = (rb.z << BUKSHIFT) | (cb.z & BUKMASK);
        b = cb.w >> BUKSHIFT; off = atomicAdd(&hist[g * NBUK + b], 1); stag[lbase[b] + off] = (rb.w << BUKSHIFT) | (cb.w & BUKMASK);
    }
    __syncthreads();

    const int eTot = min(SC_CHUNK, E - blockIdx.x * SC_CHUNK);
    int s = tid * 8;
    if (s < eTot) {
        int lo = 0, hi = NBUK - 1;
        while (lo < hi) { int mid = (lo + hi + 1) >> 1; if (lbase[mid] <= s) lo = mid; else hi = mid - 1; }
        int b = lo;
        const int e1 = min(s + 8, eTot);
        for (; s < e1; ++s) {
            while (b + 1 < NBUK && lbase[b + 1] <= s) ++b;
            binned[gbase[b] + (s - lbase[b])] = stag[s];
        }
    }
}

// per-bucket degree -> dinv, y1
__global__ __launch_bounds__(1024) void k_deg(const int* __restrict__ binned,
                                              const int* __restrict__ gofs,
                                              const float* __restrict__ x,
                                              float* __restrict__ dinv,
                                              float* __restrict__ y1) {
    __shared__ int cnt[8][BUKSZ];
    const int tid = threadIdx.x;
    for (int i = tid; i < 8 * BUKSZ; i += 1024) (&cnt[0][0])[i] = 0;
    __syncthreads();
    const int b = blockIdx.x, g = tid >> 7;
    for (int sg = 0; sg < NGRP; ++sg) {
        const int s0 = b * CAP + sg * SUBCAP;
        const int n = gofs[(b * NGRP + sg) * GSTRIDE];
        const int n4 = n >> 2;
        const int4* b4 = (const int4*)(binned + s0);
        for (int i = tid; i < n4; i += 1024) {
            int4 p = b4[i];
            atomicAdd(&cnt[g][p.x & BUKMASK], 1);
            atomicAdd(&cnt[g][p.y & BUKMASK], 1);
            atomicAdd(&cnt[g][p.z & BUKMASK], 1);
            atomicAdd(&cnt[g][p.w & BUKMASK], 1);
        }
        if (tid < (n & 3)) atomicAdd(&cnt[g][binned[s0 + (n4 << 2) + tid] & BUKMASK], 1);
    }
    __syncthreads();
    if (tid < BUKSZ) {
        int v = (b << BUKSHIFT) + tid;
        if (v < N) {
            int c = 0;
            #pragma unroll
            for (int q = 0; q < 8; ++q) c += cnt[q][tid];
            float d = rsqrtf(1.0f + (float)c);
            dinv[v] = d;
            y1[v] = d * x[v];
        }
    }
}

// per-bucket acc1 -> m
__global__ __launch_bounds__(1024) void k_acc1(const int* __restrict__ binned,
                                               const int* __restrict__ gofs,
                                               const float* __restrict__ y1,
                                               const float* __restrict__ dinv,
                                               float* __restrict__ m) {
    __shared__ float acc[8][BUKSZ];
    const int tid = threadIdx.x;
    for (int i = tid; i < 8 * BUKSZ; i += 1024) (&acc[0][0])[i] = 0.f;
    __syncthreads();
    const int b = blockIdx.x, g = tid >> 7;
    for (int sg = 0; sg < NGRP; ++sg) {
        const int s0 = b * CAP + sg * SUBCAP;
        const int n = gofs[(b * NGRP + sg) * GSTRIDE];
        const int n4 = n >> 2;
        const int4* b4 = (const int4*)(binned + s0);
        for (int i = tid; i < n4; i += 1024) {
            int4 p = b4[i];
            atomicAdd(&acc[g][p.x & BUKMASK], y1[p.x >> BUKSHIFT]);
            atomicAdd(&acc[g][p.y & BUKMASK], y1[p.y >> BUKSHIFT]);
            atomicAdd(&acc[g][p.z & BUKMASK], y1[p.z >> BUKSHIFT]);
            atomicAdd(&acc[g][p.w & BUKMASK], y1[p.w >> BUKSHIFT]);
        }
        if (tid < (n & 3)) {
            int p = binned[s0 + (n4 << 2) + tid];
            atomicAdd(&acc[g][p & BUKMASK], y1[p >> BUKSHIFT]);
        }
    }
    __syncthreads();
    if (tid < BUKSZ) {
        int v = (b << BUKSHIFT) + tid;
        if (v < N) {
            float a = 0.f;
            #pragma unroll
            for (int q = 0; q < 8; ++q) a += acc[q][tid];
            float d = dinv[v];
            float s = d * a + d * y1[v];
            m[v] = d * s;
        }
    }
}

// per-bucket tpos/tneg -> h2 -> per-block partial column sums
__global__ __launch_bounds__(1024) void k_acc2(const int* __restrict__ binned,
                                               const int* __restrict__ gofs,
                                               const float* __restrict__ m,
                                               const float* __restrict__ dinv,
                                               const float* __restrict__ W1,
                                               const float* __restrict__ W2,
                                               float* __restrict__ partials) {
    __shared__ float tp[8][BUKSZ], tn[8][BUKSZ];
    __shared__ float sP[16], sM[16], sAcc[16];
    const int tid = threadIdx.x;
    if (tid < 16) {
        float p = 0.f, q = 0.f;
        for (int k = 0; k < 16; ++k) {
            float w1 = W1[k];
            float w2 = W2[k * 16 + tid];
            p += fmaxf(w1, 0.f) * w2;
            q += fminf(w1, 0.f) * w2;
        }
        sP[tid] = p; sM[tid] = q; sAcc[tid] = 0.f;
    }
    for (int i = tid; i < 8 * BUKSZ; i += 1024) { (&tp[0][0])[i] = 0.f; (&tn[0][0])[i] = 0.f; }
    __syncthreads();
    const int b = blockIdx.x, g = tid >> 7;
    for (int sg = 0; sg < NGRP; ++sg) {
        const int s0 = b * CAP + sg * SUBCAP;
        const int n = gofs[(b * NGRP + sg) * GSTRIDE];
        const int n4 = n >> 2;
        const int4* b4 = (const int4*)(binned + s0);
        for (int i = tid; i < n4; i += 1024) {
            int4 p = b4[i];
            float v0 = m[p.x >> BUKSHIFT], v1 = m[p.y >> BUKSHIFT];
            float v2 = m[p.z >> BUKSHIFT], v3 = m[p.w >> BUKSHIFT];
            atomicAdd(v0 >= 0.f ? &tp[g][p.x & BUKMASK] : &tn[g][p.x & BUKMASK], v0);
            atomicAdd(v1 >= 0.f ? &tp[g][p.y & BUKMASK] : &tn[g][p.y & BUKMASK], v1);
            atomicAdd(v2 >= 0.f ? &tp[g][p.z & BUKMASK] : &tn[g][p.z & BUKMASK], v2);
            atomicAdd(v3 >= 0.f ? &tp[g][p.w & BUKMASK] : &tn[g][p.w & BUKMASK], v3);
        }
        if (tid < (n & 3)) {
            int p = binned[s0 + (n4 << 2) + tid];
            float val = m[p >> BUKSHIFT];
            atomicAdd(val >= 0.f ? &tp[g][p & BUKMASK] : &tn[g][p & BUKMASK], val);
        }
    }
    __syncthreads();
    float alpha = 0.f, beta = 0.f;
    if (tid < BUKSZ) {
        int v = (b << BUKSHIFT) + tid;
        if (v < N) {
            float a = 0.f, bb = 0.f;
            #pragma unroll
            for (int q = 0; q < 8; ++q) { a += tp[q][tid]; bb += tn[q][tid]; }
            float d = dinv[v], mv = m[v];
            alpha = d * a;
            beta  = d * bb;
            float self = d * mv;
            if (mv >= 0.f) alpha += self; else beta += self;
        }
    }
    const int lane = tid & 63;
    for (int j = 0; j < 16; ++j) {
        float h = fmaxf(alpha * sP[j] + beta * sM[j], 0.f);
        #pragma unroll
        for (int off = 32; off > 0; off >>= 1) h += __shfl_down(h, off);
        if (lane == 0 && h != 0.f) atomicAdd(&sAcc[j], h);
    }
    __syncthreads();
    if (tid < 16) partials[b * 16 + tid] = sAcc[tid];
}

// reduce partials[NBUK][16] -> mean -> out = g @ W3 + b
__global__ void k_out(const float* __restrict__ partials, const float* __restrict__ W3,
                      const float* __restrict__ b, float* __restrict__ out) {
    __shared__ float s[16][16];
    int j = threadIdx.x & 15;
    int g = threadIdx.x >> 4;
    float acc = 0.f;
    for (int blk = g; blk < NBUK; blk += 16) acc += partials[blk * 16 + j];
    s[g][j] = acc;
    __syncthreads();
    if (threadIdx.x < 16) {
        float tot = 0.f;
        #pragma unroll
        for (int gg = 0; gg < 16; ++gg) tot += s[gg][threadIdx.x];
        s[0][threadIdx.x] = tot * (1.0f / (float)N);
    }
    __syncthreads();
    if (threadIdx.x < 11) {
        float acc2 = b[threadIdx.x];
        #pragma unroll
        for (int k = 0; k < 16; ++k) acc2 += s[0][k] * W3[k * 11 + threadIdx.x];
        out[threadIdx.x] = acc2;
    }
}

extern "C" void kernel_launch(void* const* d_in, const int* in_sizes, int n_in,
                              void* d_out, int out_size, void* d_ws, size_t ws_size,
                              hipStream_t stream) {
    const float* x  = (const float*)d_in[0];
    const int*   ei = (const int*)d_in[1];   // [2*E]: rows then cols (int32)
    const float* W1 = (const float*)d_in[2];
    const float* W2 = (const float*)d_in[3];
    const float* W3 = (const float*)d_in[4];
    const float* b  = (const float*)d_in[5];
    float* out = (float*)d_out;

    int*   wsi      = (int*)d_ws;
    int*   binned   = wsi;                                      // NBUK*CAP
    float* dinv     = (float*)(wsi + (size_t)NBUK * CAP);
    float* y1       = dinv + N;
    float* m        = y1 + N;
    int*   gofs     = (int*)(m + N);                            // NBUK*NGRP*GSTRIDE (counts)
    float* partials = (float*)(gofs + NBUK * NGRP * GSTRIDE);   // NBUK*16

    const int4* rows4 = (const int4*)ei;
    const int4* cols4 = (const int4*)(ei + E);

    k_init   <<<(NBUK * NGRP + 511) / 512, 512, 0, stream>>>(gofs);
    k_scatter<<<SC_BLOCKS, SC_T, 0, stream>>>(rows4, cols4, gofs, binned);
    k_deg    <<<NBUK, 1024, 0, stream>>>(binned, gofs, x, dinv, y1);
    k_acc1   <<<NBUK, 1024, 0, stream>>>(binned, gofs, y1, dinv, m);
    k_acc2   <<<NBUK, 1024, 0, stream>>>(binned, gofs, m, dinv, W1, W2, partials);
    k_out    <<<1, 256, 0, stream>>>(partials, W3, b, out);
}

// Round 11
// 118.035 us; speedup vs baseline: 3.9820x; 1.0009x over previous
//
#include <hip/hip_runtime.h>

static constexpr int N = 100000;
static constexpr int E = 3200000;
static constexpr int BUKSHIFT = 8;
static constexpr int BUKSZ = 1 << BUKSHIFT;             // 256 nodes / bucket
static constexpr int BUKMASK = BUKSZ - 1;
static constexpr int NBUK = (N + BUKSZ - 1) / BUKSZ;    // 391
static constexpr int CAP = 12288;                        // slots per bucket region
static constexpr int GSTRIDE = 16;                       // pad gofs to 64B lines
static constexpr int SC_CHUNK = 4096;
static constexpr int SC_T = 512;
static constexpr int SC_BLOCKS = (E + SC_CHUNK - 1) / SC_CHUNK;  // 782

// ws (4B): binned[NBUK*CAP] | dinv[N] | y1[N] | m[N] | gofs[NBUK*GSTRIDE] (abs offsets) | partials[NBUK*16]

__global__ void k_init(int* __restrict__ gofs) {
    int i = blockIdx.x * blockDim.x + threadIdx.x;
    if (i < NBUK) gofs[i * GSTRIDE] = i * CAP;
}

// Minimal scatter: 4-replica LDS hist -> one reservation per (block,bucket) ->
// direct computed-address global writes. No sort, no staging, no scan.
__global__ __launch_bounds__(SC_T) void k_scatter(const int4* __restrict__ rows4,
                                                  const int4* __restrict__ cols4,
                                                  int* __restrict__ gofs,
                                                  int* __restrict__ binned) {
    __shared__ int hist[4 * NBUK];   // counts, then replica-prefix bases
    __shared__ int gbase[NBUK];

    const int tid = threadIdx.x;
    const int g = tid >> 7;          // 4 replica groups of 128 threads
    for (int i = tid; i < 4 * NBUK; i += SC_T) hist[i] = 0;
    __syncthreads();

    const int nI4 = E / 4;
    const int base4 = blockIdx.x * (SC_CHUNK / 4);
    const int ia = base4 + tid, ib = base4 + SC_T + tid;
    const bool va = ia < nI4, vb = ib < nI4;
    int4 ra, ca, rb, cb;
    if (va) { ra = rows4[ia]; ca = cols4[ia]; }
    if (vb) { rb = rows4[ib]; cb = cols4[ib]; }

    if (va) {
        atomicAdd(&hist[g * NBUK + (ca.x >> BUKSHIFT)], 1);
        atomicAdd(&hist[g * NBUK + (ca.y >> BUKSHIFT)], 1);
        atomicAdd(&hist[g * NBUK + (ca.z >> BUKSHIFT)], 1);
        atomicAdd(&hist[g * NBUK + (ca.w >> BUKSHIFT)], 1);
    }
    if (vb) {
        atomicAdd(&hist[g * NBUK + (cb.x >> BUKSHIFT)], 1);
        atomicAdd(&hist[g * NBUK + (cb.y >> BUKSHIFT)], 1);
        atomicAdd(&hist[g * NBUK + (cb.z >> BUKSHIFT)], 1);
        atomicAdd(&hist[g * NBUK + (cb.w >> BUKSHIFT)], 1);
    }
    __syncthreads();

    if (tid < NBUK) {
        int h0 = hist[0 * NBUK + tid], h1 = hist[1 * NBUK + tid];
        int h2 = hist[2 * NBUK + tid], h3 = hist[3 * NBUK + tid];
        hist[0 * NBUK + tid] = 0;
        hist[1 * NBUK + tid] = h0;
        hist[2 * NBUK + tid] = h0 + h1;
        hist[3 * NBUK + tid] = h0 + h1 + h2;
        int c = h0 + h1 + h2 + h3;
        gbase[tid] = c ? atomicAdd(&gofs[tid * GSTRIDE], c) : 0;
    }
    __syncthreads();

    if (va) {
        int b, off;
        b = ca.x >> BUKSHIFT; off = atomicAdd(&hist[g * NBUK + b], 1); binned[gbase[b] + off] = (ra.x << BUKSHIFT) | (ca.x & BUKMASK);
        b = ca.y >> BUKSHIFT; off = atomicAdd(&hist[g * NBUK + b], 1); binned[gbase[b] + off] = (ra.y << BUKSHIFT) | (ca.y & BUKMASK);
        b = ca.z >> BUKSHIFT; off = atomicAdd(&hist[g * NBUK + b], 1); binned[gbase[b] + off] = (ra.z << BUKSHIFT) | (ca.z & BUKMASK);
        b = ca.w >> BUKSHIFT; off = atomicAdd(&hist[g * NBUK + b], 1); binned[gbase[b] + off] = (ra.w << BUKSHIFT) | (ca.w & BUKMASK);
    }
    if (vb) {
        int b, off;
        b = cb.x >> BUKSHIFT; off = atomicAdd(&hist[g * NBUK + b], 1); binned[gbase[b] + off] = (rb.x << BUKSHIFT) | (cb.x & BUKMASK);
        b = cb.y >> BUKSHIFT; off = atomicAdd(&hist[g * NBUK + b], 1); binned[gbase[b] + off] = (rb.y << BUKSHIFT) | (cb.y & BUKMASK);
        b = cb.z >> BUKSHIFT; off = atomicAdd(&hist[g * NBUK + b], 1); binned[gbase[b] + off] = (rb.z << BUKSHIFT) | (cb.z & BUKMASK);
        b = cb.w >> BUKSHIFT; off = atomicAdd(&hist[g * NBUK + b], 1); binned[gbase[b] + off] = (rb.w << BUKSHIFT) | (cb.w & BUKMASK);
    }
}

// per-bucket degree -> dinv, y1 (single contiguous segment per bucket)
__global__ __launch_bounds__(1024) void k_deg(const int* __restrict__ binned,
                                              const int* __restrict__ gofs,
                                              const float* __restrict__ x,
                                              float* __restrict__ dinv,
                                              float* __restrict__ y1) {
    __shared__ int cnt[8][BUKSZ];
    const int tid = threadIdx.x;
    for (int i = tid; i < 8 * BUKSZ; i += 1024) (&cnt[0][0])[i] = 0;
    __syncthreads();
    const int b = blockIdx.x, g = tid >> 7;
    const int s0 = b * CAP;
    const int n = gofs[b * GSTRIDE] - s0;
    const int n4 = n >> 2;
    const int4* b4 = (const int4*)(binned + s0);
    for (int i = tid; i < n4; i += 1024) {
        int4 p = b4[i];
        atomicAdd(&cnt[g][p.x & BUKMASK], 1);
        atomicAdd(&cnt[g][p.y & BUKMASK], 1);
        atomicAdd(&cnt[g][p.z & BUKMASK], 1);
        atomicAdd(&cnt[g][p.w & BUKMASK], 1);
    }
    if (tid < (n & 3)) atomicAdd(&cnt[g][binned[s0 + (n4 << 2) + tid] & BUKMASK], 1);
    __syncthreads();
    if (tid < BUKSZ) {
        int v = (b << BUKSHIFT) + tid;
        if (v < N) {
            int c = 0;
            #pragma unroll
            for (int q = 0; q < 8; ++q) c += cnt[q][tid];
            float d = rsqrtf(1.0f + (float)c);
            dinv[v] = d;
            y1[v] = d * x[v];
        }
    }
}

// per-bucket acc1 -> m
__global__ __launch_bounds__(1024) void k_acc1(const int* __restrict__ binned,
                                               const int* __restrict__ gofs,
                                               const float* __restrict__ y1,
                                               const float* __restrict__ dinv,
                                               float* __restrict__ m) {
    __shared__ float acc[8][BUKSZ];
    const int tid = threadIdx.x;
    for (int i = tid; i < 8 * BUKSZ; i += 1024) (&acc[0][0])[i] = 0.f;
    __syncthreads();
    const int b = blockIdx.x, g = tid >> 7;
    const int s0 = b * CAP;
    const int n = gofs[b * GSTRIDE] - s0;
    const int n4 = n >> 2;
    const int4* b4 = (const int4*)(binned + s0);
    for (int i = tid; i < n4; i += 1024) {
        int4 p = b4[i];
        atomicAdd(&acc[g][p.x & BUKMASK], y1[p.x >> BUKSHIFT]);
        atomicAdd(&acc[g][p.y & BUKMASK], y1[p.y >> BUKSHIFT]);
        atomicAdd(&acc[g][p.z & BUKMASK], y1[p.z >> BUKSHIFT]);
        atomicAdd(&acc[g][p.w & BUKMASK], y1[p.w >> BUKSHIFT]);
    }
    if (tid < (n & 3)) {
        int p = binned[s0 + (n4 << 2) + tid];
        atomicAdd(&acc[g][p & BUKMASK], y1[p >> BUKSHIFT]);
    }
    __syncthreads();
    if (tid < BUKSZ) {
        int v = (b << BUKSHIFT) + tid;
        if (v < N) {
            float a = 0.f;
            #pragma unroll
            for (int q = 0; q < 8; ++q) a += acc[q][tid];
            float d = dinv[v];
            float s = d * a + d * y1[v];
            m[v] = d * s;
        }
    }
}

// per-bucket tpos/tneg -> h2 -> per-block partial column sums
__global__ __launch_bounds__(1024) void k_acc2(const int* __restrict__ binned,
                                               const int* __restrict__ gofs,
                                               const float* __restrict__ m,
                                               const float* __restrict__ dinv,
                                               const float* __restrict__ W1,
                                               const float* __restrict__ W2,
                                               float* __restrict__ partials) {
    __shared__ float tp[8][BUKSZ], tn[8][BUKSZ];
    __shared__ float sP[16], sM[16], sAcc[16];
    const int tid = threadIdx.x;
    if (tid < 16) {
        float p = 0.f, q = 0.f;
        for (int k = 0; k < 16; ++k) {
            float w1 = W1[k];
            float w2 = W2[k * 16 + tid];
            p += fmaxf(w1, 0.f) * w2;
            q += fminf(w1, 0.f) * w2;
        }
        sP[tid] = p; sM[tid] = q; sAcc[tid] = 0.f;
    }
    for (int i = tid; i < 8 * BUKSZ; i += 1024) { (&tp[0][0])[i] = 0.f; (&tn[0][0])[i] = 0.f; }
    __syncthreads();
    const int b = blockIdx.x, g = tid >> 7;
    const int s0 = b * CAP;
    const int n = gofs[b * GSTRIDE] - s0;
    const int n4 = n >> 2;
    const int4* b4 = (const int4*)(binned + s0);
    for (int i = tid; i < n4; i += 1024) {
        int4 p = b4[i];
        float v0 = m[p.x >> BUKSHIFT], v1 = m[p.y >> BUKSHIFT];
        float v2 = m[p.z >> BUKSHIFT], v3 = m[p.w >> BUKSHIFT];
        atomicAdd(v0 >= 0.f ? &tp[g][p.x & BUKMASK] : &tn[g][p.x & BUKMASK], v0);
        atomicAdd(v1 >= 0.f ? &tp[g][p.y & BUKMASK] : &tn[g][p.y & BUKMASK], v1);
        atomicAdd(v2 >= 0.f ? &tp[g][p.z & BUKMASK] : &tn[g][p.z & BUKMASK], v2);
        atomicAdd(v3 >= 0.f ? &tp[g][p.w & BUKMASK] : &tn[g][p.w & BUKMASK], v3);
    }
    if (tid < (n & 3)) {
        int p = binned[s0 + (n4 << 2) + tid];
        float val = m[p >> BUKSHIFT];
        atomicAdd(val >= 0.f ? &tp[g][p & BUKMASK] : &tn[g][p & BUKMASK], val);
    }
    __syncthreads();
    float alpha = 0.f, beta = 0.f;
    if (tid < BUKSZ) {
        int v = (b << BUKSHIFT) + tid;
        if (v < N) {
            float a = 0.f, bb = 0.f;
            #pragma unroll
            for (int q = 0; q < 8; ++q) { a += tp[q][tid]; bb += tn[q][tid]; }
            float d = dinv[v], mv = m[v];
            alpha = d * a;
            beta  = d * bb;
            float self = d * mv;
            if (mv >= 0.f) alpha += self; else beta += self;
        }
    }
    const int lane = tid & 63;
    for (int j = 0; j < 16; ++j) {
        float h = fmaxf(alpha * sP[j] + beta * sM[j], 0.f);
        #pragma unroll
        for (int off = 32; off > 0; off >>= 1) h += __shfl_down(h, off);
        if (lane == 0 && h != 0.f) atomicAdd(&sAcc[j], h);
    }
    __syncthreads();
    if (tid < 16) partials[b * 16 + tid] = sAcc[tid];
}

// reduce partials[NBUK][16] -> mean -> out = g @ W3 + b
__global__ void k_out(const float* __restrict__ partials, const float* __restrict__ W3,
                      const float* __restrict__ b, float* __restrict__ out) {
    __shared__ float s[16][16];
    int j = threadIdx.x & 15;
    int g = threadIdx.x >> 4;
    float acc = 0.f;
    for (int blk = g; blk < NBUK; blk += 16) acc += partials[blk * 16 + j];
    s[g][j] = acc;
    __syncthreads();
    if (threadIdx.x < 16) {
        float tot = 0.f;
        #pragma unroll
        for (int gg = 0; gg < 16; ++gg) tot += s[gg][threadIdx.x];
        s[0][threadIdx.x] = tot * (1.0f / (float)N);
    }
    __syncthreads();
    if (threadIdx.x < 11) {
        float acc2 = b[threadIdx.x];
        #pragma unroll
        for (int k = 0; k < 16; ++k) acc2 += s[0][k] * W3[k * 11 + threadIdx.x];
        out[threadIdx.x] = acc2;
    }
}

extern "C" void kernel_launch(void* const* d_in, const int* in_sizes, int n_in,
                              void* d_out, int out_size, void* d_ws, size_t ws_size,
                              hipStream_t stream) {
    const float* x  = (const float*)d_in[0];
    const int*   ei = (const int*)d_in[1];   // [2*E]: rows then cols (int32)
    const float* W1 = (const float*)d_in[2];
    const float* W2 = (const float*)d_in[3];
    const float* W3 = (const float*)d_in[4];
    const float* b  = (const float*)d_in[5];
    float* out = (float*)d_out;

    int*   wsi      = (int*)d_ws;
    int*   binned   = wsi;                                      // NBUK*CAP
    float* dinv     = (float*)(wsi + (size_t)NBUK * CAP);
    float* y1       = dinv + N;
    float* m        = y1 + N;
    int*   gofs     = (int*)(m + N);                            // NBUK*GSTRIDE (abs offsets)
    float* partials = (float*)(gofs + NBUK * GSTRIDE);          // NBUK*16

    const int4* rows4 = (const int4*)ei;
    const int4* cols4 = (const int4*)(ei + E);

    k_init   <<<1, 512, 0, stream>>>(gofs);
    k_scatter<<<SC_BLOCKS, SC_T, 0, stream>>>(rows4, cols4, gofs, binned);
    k_deg    <<<NBUK, 1024, 0, stream>>>(binned, gofs, x, dinv, y1);
    k_acc1   <<<NBUK, 1024, 0, stream>>>(binned, gofs, y1, dinv, m);
    k_acc2   <<<NBUK, 1024, 0, stream>>>(binned, gofs, m, dinv, W1, W2, partials);
    k_out    <<<1, 256, 0, stream>>>(partials, W3, b, out);
}